// Round 3
// baseline (644.820 us; speedup 1.0000x reference)
//
#include <hip/hip_runtime.h>
#include <cstdint>
#include <cstddef>

// HyenaCascade on MI355X — 3-phase chunked bidirectional 16-state scan.
// R2 -> R3: CH=32 (2x waves -> 100% occupancy ceiling), chunk = slowest grid
// dim (L2 row sharing across heads), unguarded loads on interior chunks,
// packed f32x2 residue reduction.

#define Bn 2
#define Ln 8192
#define HIDn 1024
#define HEADSn 16
#define STATEn 16
#define THIDn 3072  // 3*HID

typedef __attribute__((ext_vector_type(2))) float f32x2;

template <bool G>
__device__ __forceinline__ float ldu(const float* __restrict__ base, int t) {
    if constexpr (G)
        return ((unsigned)t < (unsigned)Ln) ? base[(size_t)t * THIDn] : 0.0f;
    else
        return base[(size_t)t * THIDn];
}

// ---------------- Phase A: per-chunk local scan finals ----------------
template <int CH, bool G>
__device__ __forceinline__ void phaseA_body(
    const float* __restrict__ u1, const float* __restrict__ uv,
    float w10, float w11, float w12, float wv0, float wv1, float wv2,
    const f32x2* __restrict__ p2, int t0,
    f32x2* __restrict__ cF2, f32x2* __restrict__ cG2) {
    const int t1 = t0 + CH - 1;
    // ---- forward local scan ----
    {
        f32x2 f2[8];
#pragma unroll
        for (int s = 0; s < 8; ++s) f2[s] = (f32x2){0.0f, 0.0f};
        float a0 = ldu<G>(u1, t0 - 2), a1 = ldu<G>(u1, t0 - 1), a2 = ldu<G>(u1, t0), a3 = ldu<G>(u1, t0 + 1);
        float v0 = ldu<G>(uv, t0 - 2), v1 = ldu<G>(uv, t0 - 1), v2 = ldu<G>(uv, t0), v3 = ldu<G>(uv, t0 + 1);
#pragma unroll 8
        for (int tt = 0; tt < CH; ++tt) {
            const int t = t0 + tt;
            const float a4 = ldu<G>(u1, t + 2);
            const float v4 = ldu<G>(uv, t + 2);
            const float z1 = fmaf(w10, a0 + a4, fmaf(w11, a1 + a3, w12 * a2));
            const float zv = fmaf(wv0, v0 + v4, fmaf(wv1, v1 + v3, wv2 * v2));
            const float x = z1 * zv;
            const f32x2 xb = (f32x2){x, x};
#pragma unroll
            for (int s = 0; s < 8; ++s) f2[s] = __builtin_elementwise_fma(p2[s], f2[s], xb);
            a0 = a1; a1 = a2; a2 = a3; a3 = a4;
            v0 = v1; v1 = v2; v2 = v3; v3 = v4;
        }
#pragma unroll
        for (int s = 0; s < 8; ++s) cF2[s] = f2[s];
    }
    // ---- backward local scan (reloads are L1/L2-hot) ----
    {
        f32x2 g2[8];
#pragma unroll
        for (int s = 0; s < 8; ++s) g2[s] = (f32x2){0.0f, 0.0f};
        float a4 = ldu<G>(u1, t1 + 2), a3 = ldu<G>(u1, t1 + 1), a2 = ldu<G>(u1, t1), a1 = ldu<G>(u1, t1 - 1);
        float v4 = ldu<G>(uv, t1 + 2), v3 = ldu<G>(uv, t1 + 1), v2 = ldu<G>(uv, t1), v1 = ldu<G>(uv, t1 - 1);
#pragma unroll 8
        for (int tt = CH - 1; tt >= 0; --tt) {
            const int t = t0 + tt;
            const float a0 = ldu<G>(u1, t - 2);
            const float v0 = ldu<G>(uv, t - 2);
            const float z1 = fmaf(w10, a0 + a4, fmaf(w11, a1 + a3, w12 * a2));
            const float zv = fmaf(wv0, v0 + v4, fmaf(wv1, v1 + v3, wv2 * v2));
            const float x = z1 * zv;
            const f32x2 xb = (f32x2){x, x};
#pragma unroll
            for (int s = 0; s < 8; ++s) g2[s] = __builtin_elementwise_fma(p2[s], g2[s], xb);
            a4 = a3; a3 = a2; a2 = a1; a1 = a0;
            v4 = v3; v3 = v2; v2 = v1; v1 = v0;
        }
#pragma unroll
        for (int s = 0; s < 8; ++s) cG2[s] = g2[s];
    }
}

template <int CH>
__global__ __launch_bounds__(64, 8) void hyena_phaseA(
    const float* __restrict__ u, const float* __restrict__ sfw,
    const float* __restrict__ lp,
    float* __restrict__ carryF, float* __restrict__ carryG) {
    constexpr int NC = Ln / CH;
    const int j = threadIdx.x;
    const int h = blockIdx.x;
    const int b = blockIdx.y;
    const int chunk = blockIdx.z;     // slowest dim: co-resident blocks share rows
    const int c1 = h * 192 + 64 + j;  // x1 column
    const int cv = c1 + 64;           // v column
    const int t0 = chunk * CH;

    const float* u1 = u + (size_t)b * Ln * THIDn + c1;
    const float* uv = u + (size_t)b * Ln * THIDn + cv;
    const float w10 = sfw[c1 * 3 + 0], w11 = sfw[c1 * 3 + 1], w12 = 2.0f * sfw[c1 * 3 + 2];
    const float wv0 = sfw[cv * 3 + 0], wv1 = sfw[cv * 3 + 1], wv2 = 2.0f * sfw[cv * 3 + 2];

    f32x2 p2[8];
#pragma unroll
    for (int s = 0; s < 8; ++s) p2[s] = (f32x2){expf(lp[2 * s]), expf(lp[2 * s + 1])};

    const int gch = b * HIDn + h * 64 + j;
    const size_t base = ((size_t)chunk * (Bn * HIDn) + gch) * 16;  // chunk-major
    f32x2* cF2 = (f32x2*)(carryF + base);
    f32x2* cG2 = (f32x2*)(carryG + base);

    if (chunk > 0 && chunk < NC - 1)
        phaseA_body<CH, false>(u1, uv, w10, w11, w12, wv0, wv1, wv2, p2, t0, cF2, cG2);
    else
        phaseA_body<CH, true>(u1, uv, w10, w11, w12, wv0, wv1, wv2, p2, t0, cF2, cG2);
}

// ---------------- Phase B: carry combine across chunks (in-place) ----------------
template <int CH>
__global__ __launch_bounds__(256) void hyena_phaseB(
    const float* __restrict__ lp,
    float* __restrict__ carryF, float* __restrict__ carryG) {
    constexpr int NC = Ln / CH;
    constexpr int UB = 16;
    const int dir = blockIdx.x >> 7;                          // 0..127 fwd, 128..255 bwd
    const int ht = ((blockIdx.x & 127) << 8) + threadIdx.x;   // 0..32767
    const int s = ht & 15;
    const int gch = ht >> 4;                                  // 0..2047
    const float pCH = expf(lp[s] * (float)CH);
    float c = 0.0f;
    if (dir == 0) {
        for (int k0 = 0; k0 < NC; k0 += UB) {
            float loc[UB];
#pragma unroll
            for (int q = 0; q < UB; ++q)
                loc[q] = carryF[((size_t)(k0 + q) * (Bn * HIDn) + gch) * 16 + s];
#pragma unroll
            for (int q = 0; q < UB; ++q) {
                carryF[((size_t)(k0 + q) * (Bn * HIDn) + gch) * 16 + s] = c;
                c = fmaf(pCH, c, loc[q]);
            }
        }
    } else {
        for (int k0 = NC - UB; k0 >= 0; k0 -= UB) {
            float loc[UB];
#pragma unroll
            for (int q = UB - 1; q >= 0; --q)
                loc[q] = carryG[((size_t)(k0 + q) * (Bn * HIDn) + gch) * 16 + s];
#pragma unroll
            for (int q = UB - 1; q >= 0; --q) {
                carryG[((size_t)(k0 + q) * (Bn * HIDn) + gch) * 16 + s] = c;
                c = fmaf(pCH, c, loc[q]);
            }
        }
    }
}

// ---------------- Phase C: seeded scans + gating + output ----------------
template <int CH, bool G>
__device__ __forceinline__ void phaseC_body(
    const float* __restrict__ u2, const float* __restrict__ u1,
    const float* __restrict__ uv, float* __restrict__ op,
    float w20, float w21, float w22, float w10, float w11, float w12,
    float wv0, float wv1, float wv2,
    const f32x2* __restrict__ p2, const f32x2* __restrict__ rr2,
    float dI, int t0,
    const f32x2* __restrict__ cF2, const f32x2* __restrict__ cG2) {
    const int t1 = t0 + CH - 1;
    // ---- forward: causal branch, y_c -> out ----
    {
        f32x2 f2[8];
#pragma unroll
        for (int s = 0; s < 8; ++s) f2[s] = cF2[s];
        float a0 = ldu<G>(u1, t0 - 2), a1 = ldu<G>(u1, t0 - 1), a2 = ldu<G>(u1, t0), a3 = ldu<G>(u1, t0 + 1);
        float v0 = ldu<G>(uv, t0 - 2), v1 = ldu<G>(uv, t0 - 1), v2 = ldu<G>(uv, t0), v3 = ldu<G>(uv, t0 + 1);
#pragma unroll 8
        for (int tt = 0; tt < CH; ++tt) {
            const int t = t0 + tt;
            const float a4 = ldu<G>(u1, t + 2);
            const float v4 = ldu<G>(uv, t + 2);
            const float z1 = fmaf(w10, a0 + a4, fmaf(w11, a1 + a3, w12 * a2));
            const float zv = fmaf(wv0, v0 + v4, fmaf(wv1, v1 + v3, wv2 * v2));
            const float x = z1 * zv;
            const f32x2 xb = (f32x2){x, x};
#pragma unroll
            for (int s = 0; s < 8; ++s) f2[s] = __builtin_elementwise_fma(p2[s], f2[s], xb);
            f32x2 acc0 = rr2[0] * f2[0], acc1 = rr2[1] * f2[1];
            f32x2 acc2 = rr2[2] * f2[2], acc3 = rr2[3] * f2[3];
            acc0 = __builtin_elementwise_fma(rr2[4], f2[4], acc0);
            acc1 = __builtin_elementwise_fma(rr2[5], f2[5], acc1);
            acc2 = __builtin_elementwise_fma(rr2[6], f2[6], acc2);
            acc3 = __builtin_elementwise_fma(rr2[7], f2[7], acc3);
            const f32x2 sum = (acc0 + acc1) + (acc2 + acc3);
            op[(size_t)t * HIDn] = sum.x + sum.y;
            a0 = a1; a1 = a2; a2 = a3; a3 = a4;
            v0 = v1; v1 = v2; v2 = v3; v3 = v4;
        }
    }
    // ---- backward: anti-causal + skip + gate, same-thread RMW on out ----
    {
        f32x2 g2[8];
#pragma unroll
        for (int s = 0; s < 8; ++s) g2[s] = cG2[s];
        float a4 = ldu<G>(u1, t1 + 2), a3 = ldu<G>(u1, t1 + 1), a2 = ldu<G>(u1, t1), a1 = ldu<G>(u1, t1 - 1);
        float v4 = ldu<G>(uv, t1 + 2), v3 = ldu<G>(uv, t1 + 1), v2 = ldu<G>(uv, t1), v1 = ldu<G>(uv, t1 - 1);
        float e4 = ldu<G>(u2, t1 + 2), e3 = ldu<G>(u2, t1 + 1), e2 = ldu<G>(u2, t1), e1 = ldu<G>(u2, t1 - 1);
#pragma unroll 8
        for (int tt = CH - 1; tt >= 0; --tt) {
            const int t = t0 + tt;
            const float yc = op[(size_t)t * HIDn];  // own earlier store; L2-hot
            const float a0 = ldu<G>(u1, t - 2);
            const float v0 = ldu<G>(uv, t - 2);
            const float e0 = ldu<G>(u2, t - 2);
            const float z1 = fmaf(w10, a0 + a4, fmaf(w11, a1 + a3, w12 * a2));
            const float zv = fmaf(wv0, v0 + v4, fmaf(wv1, v1 + v3, wv2 * v2));
            const float z2 = fmaf(w20, e0 + e4, fmaf(w21, e1 + e3, w22 * e2));
            const float x = z1 * zv;
            const f32x2 xb = (f32x2){x, x};
#pragma unroll
            for (int s = 0; s < 8; ++s) g2[s] = __builtin_elementwise_fma(p2[s], g2[s], xb);
            f32x2 acc0 = rr2[0] * g2[0], acc1 = rr2[1] * g2[1];
            f32x2 acc2 = rr2[2] * g2[2], acc3 = rr2[3] * g2[3];
            acc0 = __builtin_elementwise_fma(rr2[4], g2[4], acc0);
            acc1 = __builtin_elementwise_fma(rr2[5], g2[5], acc1);
            acc2 = __builtin_elementwise_fma(rr2[6], g2[6], acc2);
            acc3 = __builtin_elementwise_fma(rr2[7], g2[7], acc3);
            const f32x2 sum = (acc0 + acc1) + (acc2 + acc3);
            const float ya = sum.x + sum.y;
            op[(size_t)t * HIDn] = (yc + ya + dI * x) * z2;
            a4 = a3; a3 = a2; a2 = a1; a1 = a0;
            v4 = v3; v3 = v2; v2 = v1; v1 = v0;
            e4 = e3; e3 = e2; e2 = e1; e1 = e0;
        }
    }
}

template <int CH>
__global__ __launch_bounds__(64, 8) void hyena_phaseC(
    const float* __restrict__ u, const float* __restrict__ sfw,
    const float* __restrict__ lp, const float* __restrict__ res,
    const float* __restrict__ Dp,
    const float* __restrict__ carryF, const float* __restrict__ carryG,
    float* __restrict__ out) {
    constexpr int NC = Ln / CH;
    const int j = threadIdx.x;
    const int h = blockIdx.x;
    const int b = blockIdx.y;
    const int chunk = blockIdx.z;
    const int c2 = h * 192 + j;       // x2 (gate)
    const int c1 = c2 + 64;           // x1
    const int cv = c2 + 128;          // v
    const int i = h * 64 + j;
    const int gch = b * HIDn + i;
    const int t0 = chunk * CH;

    const float* u2 = u + (size_t)b * Ln * THIDn + c2;
    const float* u1 = u + (size_t)b * Ln * THIDn + c1;
    const float* uv = u + (size_t)b * Ln * THIDn + cv;
    float* op = out + (size_t)b * Ln * HIDn + i;
    const float w20 = sfw[c2 * 3 + 0], w21 = sfw[c2 * 3 + 1], w22 = 2.0f * sfw[c2 * 3 + 2];
    const float w10 = sfw[c1 * 3 + 0], w11 = sfw[c1 * 3 + 1], w12 = 2.0f * sfw[c1 * 3 + 2];
    const float wv0 = sfw[cv * 3 + 0], wv1 = sfw[cv * 3 + 1], wv2 = 2.0f * sfw[cv * 3 + 2];

    f32x2 p2[8], rr2[8];
#pragma unroll
    for (int s = 0; s < 8; ++s) p2[s] = (f32x2){expf(lp[2 * s]), expf(lp[2 * s + 1])};
#pragma unroll
    for (int s = 0; s < 8; ++s) rr2[s] = (f32x2){res[2 * s], res[2 * s + 1]};
    const float dI = Dp[i];

    const size_t cbase = ((size_t)chunk * (Bn * HIDn) + gch) * 16;
    const f32x2* cF2 = (const f32x2*)(carryF + cbase);
    const f32x2* cG2 = (const f32x2*)(carryG + cbase);

    if (chunk > 0 && chunk < NC - 1)
        phaseC_body<CH, false>(u2, u1, uv, op, w20, w21, w22, w10, w11, w12,
                               wv0, wv1, wv2, p2, rr2, dI, t0, cF2, cG2);
    else
        phaseC_body<CH, true>(u2, u1, uv, op, w20, w21, w22, w10, w11, w12,
                              wv0, wv1, wv2, p2, rr2, dI, t0, cF2, cG2);
}

template <int CH>
static void run_all(const float* u, const float* sfw, const float* lp,
                    const float* res, const float* Dp, float* out,
                    void* ws, hipStream_t stream) {
    constexpr int NC = Ln / CH;
    float* carryF = (float*)ws;
    float* carryG = carryF + (size_t)NC * (Bn * HIDn) * 16;
    dim3 grid(HEADSn, Bn, NC);  // chunk slowest -> L2 row sharing
    hipLaunchKernelGGL((hyena_phaseA<CH>), grid, dim3(64), 0, stream,
                       u, sfw, lp, carryF, carryG);
    hipLaunchKernelGGL((hyena_phaseB<CH>), dim3(256), dim3(256), 0, stream,
                       lp, carryF, carryG);
    hipLaunchKernelGGL((hyena_phaseC<CH>), grid, dim3(64), 0, stream,
                       u, sfw, lp, res, Dp, carryF, carryG, out);
}

extern "C" void kernel_launch(void* const* d_in, const int* in_sizes, int n_in,
                              void* d_out, int out_size, void* d_ws, size_t ws_size,
                              hipStream_t stream) {
    const float* u   = (const float*)d_in[0];  // (B, L, 3*HID) fp32
    const float* sfw = (const float*)d_in[1];  // (3*HID, 1, 3)
    const float* lp  = (const float*)d_in[2];  // (1, 16, 1)
    const float* res = (const float*)d_in[3];  // (1, 16)
    const float* Dp  = (const float*)d_in[4];  // (HID,)
    float* out = (float*)d_out;                // (B, L, HID) fp32

    // carry workspace need: 2 * (L/CH) * 2048 * 16 * 4 B = 2^31/CH bytes
    const size_t need32 = ((size_t)1 << 31) / 32;  // 64 MiB at CH=32
    if (ws_size >= need32)            run_all<32>(u, sfw, lp, res, Dp, out, d_ws, stream);
    else if (ws_size >= need32 / 2)   run_all<64>(u, sfw, lp, res, Dp, out, d_ws, stream);
    else if (ws_size >= need32 / 4)   run_all<128>(u, sfw, lp, res, Dp, out, d_ws, stream);
    else                              run_all<256>(u, sfw, lp, res, Dp, out, d_ws, stream);
}